// Round 19
// baseline (88.419 us; speedup 1.0000x reference)
//
#include <hip/hip_runtime.h>

// Problem constants (from reference)
#define BQ 2
#define HQ 16
#define SQ 8192
#define DQ 128
#define STR 16
#define NWIN 511     // (8192-32)/16 + 1
#define NBLK 512     // NWIN + 1 zero block
#define WPB 8        // windows per workgroup (amortizes L2 weight re-fetch)
#define NWG_PER_HEAD 64

typedef float f32x4 __attribute__((ext_vector_type(4)));
typedef float f32x16 __attribute__((ext_vector_type(16)));
typedef short s16x8 __attribute__((ext_vector_type(8)));
typedef short s16x4 __attribute__((ext_vector_type(4)));

// LDS 53.2 KB map (R15): all bases multiples of 4096.
//   kin @0     [80 rows][256B] = 20480  (4-window chunk; reused for chunk 2)
//   s0  @20480 [128][256] = 32768       (ends 53248)
//   s1  @0     [64][256]  = 16384       (kin dead after s0 chunk 2)
//   s2  @20480 [32][256]  =  8192       (s0 dead after s1)
//   s3  @0     [16][256]  =  4096
//   s4  @28672 [8][256]   =  2048
#define R_KIN 0u
#define R_S0  20480u
#define R_S1  0u
#define R_S2  20480u
#define R_S3  0u
#define R_S4  28672u

// XOR swizzle keyed on 512B granule (G4/T2). Involution on global LDS byte
// offsets. 32x32 KEY INVARIANCE: s0 B-rows = 32rg + 16(lo5>>4) + 2(lo5&15)
// (+1 for t>=8): key (row>>1)&7 = lo5&7 (32rg, 8(lo5>>4) vanish mod 8).
// s1 B-rows = 64rg + 2lo5 (+1): key = (32rg+lo5)&7 = lo5&7. Write rows
// d = {64c+32rg+lo5, 32rg+lo5}: key (d>>1)&7 = (lo5>>1)&7. t-byte
// (t&7)<<5 | hi<<4 < 256 -> no carry into the row field; row even at t<8
// -> +256 carry-free. All verified end-to-end in R10's passing bench.
static __device__ __forceinline__ unsigned swz(unsigned b) {
    return b ^ (((b >> 9) & 7u) << 4);
}

static __device__ __forceinline__ short f2bf(float f) {
    __bf16 h = (__bf16)f;
    return __builtin_bit_cast(short, h);
}

// cheap silu: v_rcp_f32 instead of the exact-div sequence (~10 instrs)
static __device__ __forceinline__ float silu(float v) {
    return v * __builtin_amdgcn_rcpf(1.f + __expf(-v));
}

// ---- pass 0 (merged prep): weight permute + bias0 + zero-blocks ----
// ws layout (shorts):
//   wd32 s0 @0      [4ct32][16t][512]  (32768)  32x32x16 frag order
//   wd32 s1 @32768  [4ct32][16t][512]  (32768)
//   wd16 s2 @65536, s3 @98304, s4 @131072   [8ct][8kt][512] 16x16x32 order
//   wstop   @163840 [8ct][4kt][512]    (16384)
//   bias0 f32[16][128] at byte 360448
__global__ void prep_kernel(const float* __restrict__ wd,
                            const float* __restrict__ wstop,
                            const float* __restrict__ pe,
                            short* __restrict__ o,
                            float* __restrict__ bias,
                            float* __restrict__ out) {
    int blk = blockIdx.x;
    if (blk < 704) {
        int i = blk * 256 + threadIdx.x;
        if (i < 65536) {
            // 32-wide frag order for stages 0,1
            int s   = i >> 15;
            int r   = i & 32767;
            int ct  = r >> 13;
            int r2  = r & 8191;
            int t   = r2 >> 9;
            int r3  = r2 & 511;
            int ln  = r3 >> 3;
            int e   = r3 & 7;
            int ch  = ct * 32 + (ln & 31);
            int k   = t * 16 + (ln >> 5) * 8 + e;
            o[i] = f2bf(wd[((size_t)(s * 128 + ch)) * 256 + k]);
        } else if (i < 163840) {
            // 16-wide frag order for stages 2,3,4
            int j   = i - 65536;
            int s   = j >> 15;           // 0..2 -> stage 2..4
            int r   = j & 32767;
            int ct  = r >> 12;
            int r2  = r & 4095;
            int kt  = r2 >> 9;
            int r3  = r2 & 511;
            int ln  = r3 >> 3;
            int e   = r3 & 7;
            int ch  = ct * 16 + (ln & 15);
            int k   = kt * 32 + (ln >> 4) * 8 + e;
            o[i] = f2bf(wd[((size_t)((s + 2) * 128 + ch)) * 256 + k]);
        } else if (i < 180224) {
            int j   = i - 163840;
            int ct  = j >> 11;
            int r2  = j & 2047;
            int kt  = r2 >> 9;
            int r3  = r2 & 511;
            int ln  = r3 >> 3;
            int e   = r3 & 7;
            int ch  = ct * 16 + (ln & 15);
            int k   = kt * 32 + (ln >> 4) * 8 + e;
            o[i] = f2bf(wstop[ch * 128 + k]);
        }
    } else if (blk < 712) {
        int oo = (blk - 704) * 256 + threadIdx.x;   // 0..2047
        int j = oo >> 7;
        int c = oo & 127;
        const float* w  = wd + (size_t)c * 256;
        const float* p0 = pe + (2 * j) * DQ;
        const float* p1 = pe + (2 * j + 1) * DQ;
        float s = 0.f;
        #pragma unroll 4
        for (int i = 0; i < 128; ++i) s += w[i] * p0[i];
        #pragma unroll 4
        for (int i = 0; i < 128; ++i) s += w[i + 128] * p1[i];
        bias[oo] = s;
    } else {
        int i = (blk - 712) * 256 + threadIdx.x;  // 4096 = 32 heads * 128
        int bh = i >> 7, d = i & 127;
        out[(size_t)bh * NBLK * DQ + d] = 0.f;
    }
}

// ---- pass 1: fused compressor, WPB=8; s0/s1 = 32x32x16, tail = 16x16x32 ----
// 32x32 halves activation LDS reads on the two big stages (16 vs 32 B/elem)
// and runs the MFMA pipe at its better 32x32 rate. All 8 waves busy in s1
// (WPB=8 -> 64 out rows = 2 n-tiles of 32 x 4 ct32). Weight traffic
// unchanged (one A-frag covers 32 channels). Tail is R15 verbatim.
__global__ __launch_bounds__(512, 6)
void fused_kernel(const float* __restrict__ kin,
                  const short* __restrict__ wdb,
                  const float* __restrict__ bias0,
                  float* __restrict__ out) {
    __shared__ __align__(16) unsigned char lds[53248];

    const int bh = blockIdx.x >> 6;            // 0..31
    const int w0 = (blockIdx.x & 63) * WPB;    // first window of this group
    const int tid  = threadIdx.x;
    const int lane = tid & 63;
    const int wave = tid >> 6;
    const int kl   = lane >> 4;                // 16x16 tail
    const int nl   = lane & 15;
    const int lo5  = lane & 31;                // 32x32 s0/s1
    const int hi   = lane >> 5;
    const int ct32 = wave & 3;                 // 32-ch tile 0..3
    const int rg   = wave >> 2;                // row-group 0..1
    const int ct   = wave;                     // 16-ch tile (tail)

    const float* kb = kin + (size_t)bh * SQ * DQ;

    // load one 80-row kin chunk (4 windows, 50% overlap), 1280 tasks
#define LOAD_KIN(cbase) {                                                      \
        _Pragma("unroll")                                                      \
        for (int it = 0; it < 3; ++it) {                                       \
            int task = tid + it * 512;                                         \
            if (task < 1280) {                                                 \
                int rr = task >> 4;                                            \
                int c8 = task & 15;                                            \
                int srow = STR * w0 + (cbase) + rr;                            \
                if (srow > SQ - 1) srow = SQ - 1;                              \
                const float* kp = kb + (size_t)srow * DQ + c8 * 8;             \
                f32x4 a0 = *(const f32x4*)kp;                                  \
                f32x4 a1 = *(const f32x4*)(kp + 4);                            \
                s16x8 v;                                                       \
                v[0]=f2bf(a0[0]); v[1]=f2bf(a0[1]); v[2]=f2bf(a0[2]); v[3]=f2bf(a0[3]); \
                v[4]=f2bf(a1[0]); v[5]=f2bf(a1[1]); v[6]=f2bf(a1[2]); v[7]=f2bf(a1[3]); \
                *(s16x8*)(lds + swz(R_KIN + (unsigned)((rr << 8) + (c8 << 4)))) = v; \
            }                                                                  \
        } }

    // 32x32 addressing constants (see key-invariance proof above)
    const unsigned kxr = ((unsigned)(lo5 & 7)) << 4;
    const unsigned kxw = ((unsigned)((lo5 >> 1) & 7)) << 4;
    const unsigned h4  = (((unsigned)hi) << 4) ^ kxr;
    // s0 B-row base: out-row-in-chunk = 32rg+lo5 -> kin row 16*(..>>4)+2*(..&15)
    const unsigned rowb0 = R_KIN +
        ((unsigned)(32 * rg + 16 * (lo5 >> 4) + 2 * (lo5 & 15)) << 8);

    // one 32x32 stage-0 chunk: K=256 in 4 wf-quads; d = dbase + 32rg + lo5
#define S0_CHUNK(dbase) {                                                      \
        f32x16 acc;                                                            \
        _Pragma("unroll")                                                      \
        for (int a = 0; a < 4; ++a) {                                          \
            f32x4 b4 = *(const f32x4*)(bias0 + (lo5 & 15) * 128                \
                                       + ct32 * 32 + a * 8 + hi * 4);          \
            acc[4*a+0] = b4[0]; acc[4*a+1] = b4[1];                            \
            acc[4*a+2] = b4[2]; acc[4*a+3] = b4[3];                            \
        }                                                                      \
        _Pragma("unroll")                                                      \
        for (int c4 = 0; c4 < 4; ++c4) {                                       \
            s16x8 wq[4];                                                       \
            _Pragma("unroll")                                                  \
            for (int q = 0; q < 4; ++q)                                        \
                wq[q] = *(const s16x8*)(wdb + ct32 * 8192                      \
                                        + (c4 * 4 + q) * 512 + lane * 8);      \
            _Pragma("unroll")                                                  \
            for (int q = 0; q < 4; ++q) {                                      \
                const int t = c4 * 4 + q;                                      \
                unsigned addr = rowb0 + ((t >= 8) ? 256u : 0u)                 \
                              + (((unsigned)((t & 7) << 5)) ^ h4);             \
                s16x8 bb = *(const s16x8*)(lds + addr);                        \
                acc = __builtin_amdgcn_mfma_f32_32x32x16_bf16(wq[q], bb, acc, 0, 0, 0); \
            }                                                                  \
        }                                                                      \
        const unsigned d = (unsigned)((dbase) + 32 * rg + lo5);                \
        _Pragma("unroll")                                                      \
        for (int a = 0; a < 4; ++a) {                                          \
            s16x4 v;                                                           \
            v[0] = f2bf(silu(acc[4*a+0])); v[1] = f2bf(silu(acc[4*a+1]));      \
            v[2] = f2bf(silu(acc[4*a+2])); v[3] = f2bf(silu(acc[4*a+3]));      \
            *(s16x4*)(lds + R_S0 + (d << 8)                                    \
                      + (((unsigned)(ct32 * 64 + a * 16 + hi * 8)) ^ kxw)) = v;\
        }                                                                      \
    }

    LOAD_KIN(0);
    __syncthreads();   // B1: chunk 0 ready

    S0_CHUNK(0);       // windows 0..3 -> s0 rows 0..63
    __syncthreads();   // B2: chunk-0 kin reads retired

    LOAD_KIN(64);      // chunk 1 (windows 4..7)
    __syncthreads();   // B3: chunk 1 ready

    S0_CHUNK(64);      // windows 4..7 -> s0 rows 64..127
    __syncthreads();   // B4: s0 complete; kin dead

    // tail weight set (prefetched during s1 epilogue)
    s16x8 wf[8];

    // ---- stage 1 (32x32): 128 -> 64 rows; all 8 waves (2 n-tiles x 4 ct32) ----
    {
        const unsigned rowb1 = R_S0 + ((unsigned)(64 * rg + 2 * lo5) << 8);
        f32x16 acc = {};
        #pragma unroll
        for (int c4 = 0; c4 < 4; ++c4) {
            s16x8 wq[4];
            #pragma unroll
            for (int q = 0; q < 4; ++q)
                wq[q] = *(const s16x8*)(wdb + 32768 + ct32 * 8192
                                        + (c4 * 4 + q) * 512 + lane * 8);
            #pragma unroll
            for (int q = 0; q < 4; ++q) {
                const int t = c4 * 4 + q;
                unsigned addr = rowb1 + ((t >= 8) ? 256u : 0u)
                              + (((unsigned)((t & 7) << 5)) ^ h4);
                s16x8 bb = *(const s16x8*)(lds + addr);
                acc = __builtin_amdgcn_mfma_f32_32x32x16_bf16(wq[q], bb, acc, 0, 0, 0);
            }
        }
        // prefetch stage-2 (16-wide) weights across the barrier
        #pragma unroll
        for (int kt = 0; kt < 8; ++kt)
            wf[kt] = *(const s16x8*)(wdb + 2 * 32768 + ct * 4096 + kt * 512 + lane * 8);
        const unsigned d = (unsigned)(32 * rg + lo5);
        #pragma unroll
        for (int a = 0; a < 4; ++a) {
            s16x4 v;
            v[0] = f2bf(silu(acc[4*a+0])); v[1] = f2bf(silu(acc[4*a+1]));
            v[2] = f2bf(silu(acc[4*a+2])); v[3] = f2bf(silu(acc[4*a+3]));
            *(s16x4*)(lds + R_S1 + (d << 8)
                      + (((unsigned)(ct32 * 64 + a * 16 + hi * 8)) ^ kxw)) = v;
        }
    }
    __syncthreads();   // B5: s1 done; s0 dead

    // ---- tail: R15 verbatim (16x16x32, wave = 16-ch tile ct) ----
    const short* wbase = wdb + ct * 4096 + lane * 8;

#define K_HALF4(W0, W1, W2, W3, P, Q, off, accv) {                             \
        s16x8 aa0 = *(const s16x8*)((P) + (off));                              \
        s16x8 aa1 = *(const s16x8*)((Q) + (off));                              \
        s16x8 aa2 = *(const s16x8*)((P) + (off) + 128);                        \
        s16x8 aa3 = *(const s16x8*)((Q) + (off) + 128);                        \
        accv = __builtin_amdgcn_mfma_f32_16x16x32_bf16(W0, aa0, accv, 0, 0, 0); \
        accv = __builtin_amdgcn_mfma_f32_16x16x32_bf16(W1, aa1, accv, 0, 0, 0); \
        accv = __builtin_amdgcn_mfma_f32_16x16x32_bf16(W2, aa2, accv, 0, 0, 0); \
        accv = __builtin_amdgcn_mfma_f32_16x16x32_bf16(W3, aa3, accv, 0, 0, 0); }

#define K_FULL(P, Q, off, accv)                                                \
        K_HALF4(wf[0], wf[1], wf[2], wf[3], P, Q, (off),       accv)           \
        K_HALF4(wf[4], wf[5], wf[6], wf[7], P, Q, (off) + 256, accv)

#define WRITE_ROW(region, d, accv) {                                           \
        s16x4 v;                                                               \
        v[0] = f2bf(silu((accv)[0])); v[1] = f2bf(silu((accv)[1]));            \
        v[2] = f2bf(silu((accv)[2])); v[3] = f2bf(silu((accv)[3]));            \
        *(s16x4*)(lds + swz((region) + ((unsigned)(d) << 8)                    \
                            + (unsigned)(ct * 32 + kl * 8))) = v; }

#define LOAD_WF(stage_off) {                                                   \
        _Pragma("unroll")                                                      \
        for (int kt = 0; kt < 8; ++kt)                                         \
            wf[kt] = *(const s16x8*)(wbase + (stage_off) + kt * 512); }

    // ---- stage 2: 64 -> 32 rows ----
    {
        unsigned pb = swz(R_S1 + ((unsigned)(2 * nl) << 8) + (unsigned)(kl << 4));
        const unsigned char* P = lds + pb;
        const unsigned char* Q = lds + (pb ^ 64u);
        f32x4 acc0 = {}, acc1 = {};
        K_FULL(P, Q, 0,    acc0);
        K_FULL(P, Q, 8192, acc1);
        LOAD_WF(3 * 32768);
        WRITE_ROW(R_S2, nl,      acc0);
        WRITE_ROW(R_S2, 16 + nl, acc1);
    }
    __syncthreads();   // s2 done; s1 dead

    // ---- stage 3: 32 -> 16 rows ----
    {
        unsigned pb = swz(R_S2 + ((unsigned)(2 * nl) << 8) + (unsigned)(kl << 4));
        const unsigned char* P = lds + pb;
        const unsigned char* Q = lds + (pb ^ 64u);
        f32x4 acc0 = {};
        K_FULL(P, Q, 0, acc0);
        LOAD_WF(4 * 32768);
        WRITE_ROW(R_S3, nl, acc0);
    }
    __syncthreads();   // s3 done; s2 dead

    // ---- stage 4: 16 -> 8 rows (lanes nl>=8 clamped) ----
    {
        int dc = (nl < 8) ? nl : 7;
        unsigned pb = swz(R_S3 + ((unsigned)(2 * dc) << 8) + (unsigned)(kl << 4));
        const unsigned char* P = lds + pb;
        const unsigned char* Q = lds + (pb ^ 64u);
        f32x4 acc0 = {};
        K_FULL(P, Q, 0, acc0);
        // prefetch w_stop (4 frags) across the barrier
        #pragma unroll
        for (int kt = 0; kt < 4; ++kt)
            wf[kt] = *(const s16x8*)(wdb + 163840 + ct * 2048 + kt * 512 + lane * 8);
        if (nl < 8) WRITE_ROW(R_S4, nl, acc0);
    }
    __syncthreads();   // s4 done

    // ---- w_stop: 8 rows, K=128, no activation -> global f32 ----
    {
        int dc = (nl < 8) ? nl : 7;
        unsigned pb = swz(R_S4 + ((unsigned)dc << 8) + (unsigned)(kl << 4));
        const unsigned char* P = lds + pb;
        const unsigned char* Q = lds + (pb ^ 64u);
        f32x4 acc = {0.f, 0.f, 0.f, 0.f};
        K_HALF4(wf[0], wf[1], wf[2], wf[3], P, Q, 0, acc);
        int w = w0 + nl;
        if (nl < 8 && w < NWIN) {
            // lane holds channels ct*16+kl*4 .. +3 of window w: one dwordx4
            *(f32x4*)(out + ((size_t)bh * NBLK + (w + 1)) * DQ + ct * 16 + kl * 4) = acc;
        }
    }
#undef K_HALF4
#undef K_FULL
#undef WRITE_ROW
#undef LOAD_WF
#undef LOAD_KIN
#undef S0_CHUNK
}

extern "C" void kernel_launch(void* const* d_in, const int* in_sizes, int n_in,
                              void* d_out, int out_size, void* d_ws, size_t ws_size,
                              hipStream_t stream) {
    const float* kin   = (const float*)d_in[0];
    const float* pe    = (const float*)d_in[1];
    const float* wdown = (const float*)d_in[2];
    const float* wstop = (const float*)d_in[3];
    float* out = (float*)d_out;
    short* wbf  = (short*)d_ws;                       // 180224 shorts (frag-order)
    float* bias = (float*)((char*)d_ws + 360448);     // f32[2048]

    prep_kernel<<<728, 256, 0, stream>>>(wdown, wstop, pe, wbf, bias, out);
    fused_kernel<<<BQ * HQ * NWG_PER_HEAD, 512, 0, stream>>>(kin, wbf, bias, out);
}

// Round 20
// 76.549 us; speedup vs baseline: 1.1551x; 1.1551x over previous
//
#include <hip/hip_runtime.h>

// Problem constants (from reference)
#define BQ 2
#define HQ 16
#define SQ 8192
#define DQ 128
#define STR 16
#define NWIN 511     // (8192-32)/16 + 1
#define NBLK 512     // NWIN + 1 zero block
#define WPB 8        // windows per workgroup (amortizes L2 weight re-fetch)
#define NWG_PER_HEAD 64

typedef float f32x4 __attribute__((ext_vector_type(4)));
typedef short s16x8 __attribute__((ext_vector_type(8)));
typedef short s16x4 __attribute__((ext_vector_type(4)));

// LDS 53.2 KB map (all region bases multiples of 4096 -> swizzle key fields
// never perturbed by region offset):
//   kin @0     [80 rows][256B] = 20480  (4-window chunk; reused for chunk 2)
//   s0  @20480 [128][256] = 32768       (ends 53248)
//   s1  @0     [64][256]  = 16384       (kin dead after s0 chunk 2)
//   s2  @20480 [32][256]  =  8192       (s0 dead after s1)
//   s3  @0     [16][256]  =  4096       (s1 dead)
//   s4  @28672 [8][256]   =  2048       (past s2's end; s0 region dead)
#define R_KIN 0u
#define R_S0  20480u
#define R_S1  0u
#define R_S2  20480u
#define R_S3  0u
#define R_S4  28672u

// XOR swizzle keyed on 512B granule (G4/T2). Involution on global LDS byte
// offsets. HOIST SOUNDNESS (R9 proof): all B-read rows are (2nl+half)+16m ->
// key (row>>1)&7 = nl&7 invariant over m/half; n-tile deltas (4096..24576)
// and kt deltas (64..192) are adds into disjoint bit fields; bit-6 collision
// handled by the P/Q = P^64 pair (bit 7 of P is 0). HALF FOLD: row is even at
// half=0 -> bit 8 of P is 0 -> half=1 is P+256 carry-free, so ONE swz serves
// the whole stage; all reads are P/Q + compile-time immediates.
static __device__ __forceinline__ unsigned swz(unsigned b) {
    return b ^ (((b >> 9) & 7u) << 4);
}

static __device__ __forceinline__ short f2bf(float f) {
    __bf16 h = (__bf16)f;
    return __builtin_bit_cast(short, h);
}

// cheap silu: v_rcp_f32 instead of the exact-div sequence (~10 instrs)
static __device__ __forceinline__ float silu(float v) {
    return v * __builtin_amdgcn_rcpf(1.f + __expf(-v));
}

// ---- pass 0 (merged prep): weight permute + bias0 + zero-blocks ----
// ws: wd_bf frag-order [5 stages][8ct][8kt][512] (163840 sh) + wstop
// frag-order (16384 sh) + bias0 f32[16][128] at byte 360448.
__global__ void prep_kernel(const float* __restrict__ wd,
                            const float* __restrict__ wstop,
                            const float* __restrict__ pe,
                            short* __restrict__ o,
                            float* __restrict__ bias,
                            float* __restrict__ out) {
    int blk = blockIdx.x;
    if (blk < 704) {
        int i = blk * 256 + threadIdx.x;
        if (i < 163840) {
            int s   = i >> 15;
            int r   = i & 32767;
            int ct  = r >> 12;
            int r2  = r & 4095;
            int kt  = r2 >> 9;
            int r3  = r2 & 511;
            int ln  = r3 >> 3;
            int e   = r3 & 7;
            int ch  = ct * 16 + (ln & 15);
            int k   = kt * 32 + (ln >> 4) * 8 + e;
            o[i] = f2bf(wd[((size_t)(s * 128 + ch)) * 256 + k]);
        } else if (i < 180224) {
            int j   = i - 163840;
            int ct  = j >> 11;
            int r2  = j & 2047;
            int kt  = r2 >> 9;
            int r3  = r2 & 511;
            int ln  = r3 >> 3;
            int e   = r3 & 7;
            int ch  = ct * 16 + (ln & 15);
            int k   = kt * 32 + (ln >> 4) * 8 + e;
            o[i] = f2bf(wstop[ch * 128 + k]);
        }
    } else if (blk < 712) {
        int oo = (blk - 704) * 256 + threadIdx.x;   // 0..2047
        int j = oo >> 7;
        int c = oo & 127;
        const float* w  = wd + (size_t)c * 256;
        const float* p0 = pe + (2 * j) * DQ;
        const float* p1 = pe + (2 * j + 1) * DQ;
        float s = 0.f;
        #pragma unroll 4
        for (int i = 0; i < 128; ++i) s += w[i] * p0[i];
        #pragma unroll 4
        for (int i = 0; i < 128; ++i) s += w[i + 128] * p1[i];
        bias[oo] = s;
    } else {
        int i = (blk - 712) * 256 + threadIdx.x;  // 4096 = 32 heads * 128
        int bh = i >> 7, d = i & 127;
        out[(size_t)bh * NBLK * DQ + d] = 0.f;
    }
}

// ---- pass 1: fused compressor, WPB=8 ----
// Weight prefetch chain: one wf[8] set; stage s+1's frags issued before the
// stage-s ending barrier. One swz per stage. kin chunk 1 loaded directly
// between barriers. 53.2KB LDS -> 3 blocks/CU at (512,6).
__global__ __launch_bounds__(512, 6)
void fused_kernel(const float* __restrict__ kin,
                  const short* __restrict__ wdb,
                  const float* __restrict__ bias0,
                  float* __restrict__ out) {
    __shared__ __align__(16) unsigned char lds[53248];

    const int bh = blockIdx.x >> 6;            // 0..31
    const int w0 = (blockIdx.x & 63) * WPB;    // first window of this group
    const int tid  = threadIdx.x;
    const int lane = tid & 63;
    const int ct   = tid >> 6;                 // wave = channel-tile 0..7
    const int kl   = lane >> 4;                // 0..3
    const int nl   = lane & 15;                // 0..15

    const float* kb = kin + (size_t)bh * SQ * DQ;
    const short* wbase = wdb + ct * 4096 + lane * 8;   // per-wave frag base

    // load one 80-row kin chunk (4 windows, 50% overlap), 1280 tasks
#define LOAD_KIN(cbase) {                                                      \
        _Pragma("unroll")                                                      \
        for (int it = 0; it < 3; ++it) {                                       \
            int task = tid + it * 512;                                         \
            if (task < 1280) {                                                 \
                int rr = task >> 4;                                            \
                int c8 = task & 15;                                            \
                int srow = STR * w0 + (cbase) + rr;                            \
                if (srow > SQ - 1) srow = SQ - 1;                              \
                const float* kp = kb + (size_t)srow * DQ + c8 * 8;             \
                f32x4 a0 = *(const f32x4*)kp;                                  \
                f32x4 a1 = *(const f32x4*)(kp + 4);                            \
                s16x8 v;                                                       \
                v[0]=f2bf(a0[0]); v[1]=f2bf(a0[1]); v[2]=f2bf(a0[2]); v[3]=f2bf(a0[3]); \
                v[4]=f2bf(a1[0]); v[5]=f2bf(a1[1]); v[6]=f2bf(a1[2]); v[7]=f2bf(a1[3]); \
                *(s16x8*)(lds + swz(R_KIN + (unsigned)((rr << 8) + (c8 << 4)))) = v; \
            }                                                                  \
        } }

    // 4 b128 reads (P/Q + immediates) + 4 MFMAs with explicit frags
#define K_HALF4(W0, W1, W2, W3, P, Q, off, accv) {                             \
        s16x8 aa0 = *(const s16x8*)((P) + (off));                              \
        s16x8 aa1 = *(const s16x8*)((Q) + (off));                              \
        s16x8 aa2 = *(const s16x8*)((P) + (off) + 128);                        \
        s16x8 aa3 = *(const s16x8*)((Q) + (off) + 128);                        \
        accv = __builtin_amdgcn_mfma_f32_16x16x32_bf16(W0, aa0, accv, 0, 0, 0); \
        accv = __builtin_amdgcn_mfma_f32_16x16x32_bf16(W1, aa1, accv, 0, 0, 0); \
        accv = __builtin_amdgcn_mfma_f32_16x16x32_bf16(W2, aa2, accv, 0, 0, 0); \
        accv = __builtin_amdgcn_mfma_f32_16x16x32_bf16(W3, aa3, accv, 0, 0, 0); }

    // both K-halves of one n-tile (half delta = +256, carry-free)
#define K_FULL(P, Q, off, accv)                                                \
        K_HALF4(wf[0], wf[1], wf[2], wf[3], P, Q, (off),       accv)           \
        K_HALF4(wf[4], wf[5], wf[6], wf[7], P, Q, (off) + 256, accv)

    // silu + cvt + one ds_write_b64 of 4 consecutive channels
#define WRITE_ROW(region, d, accv) {                                           \
        s16x4 v;                                                               \
        v[0] = f2bf(silu((accv)[0])); v[1] = f2bf(silu((accv)[1]));            \
        v[2] = f2bf(silu((accv)[2])); v[3] = f2bf(silu((accv)[3]));            \
        *(s16x4*)(lds + swz((region) + ((unsigned)(d) << 8)                    \
                            + (unsigned)(ct * 32 + kl * 8))) = v; }

#define LOAD_WF(stage_off) {                                                   \
        _Pragma("unroll")                                                      \
        for (int kt = 0; kt < 8; ++kt)                                         \
            wf[kt] = *(const s16x8*)(wbase + (stage_off) + kt * 512); }

    // stage-0 weights issued first: latency overlaps phase A
    s16x8 wf[8];
    LOAD_WF(0);
    const f32x4 bias = *(const f32x4*)(bias0 + nl * 128 + ct * 16 + kl * 4);

    LOAD_KIN(0);
    __syncthreads();   // B1: chunk 0 ready

    // stage-0 P/Q (constant across chunks; one swz for the whole stage)
    unsigned pb0 = swz(R_KIN + ((unsigned)(2 * nl) << 8) + (unsigned)(kl << 4));
    const unsigned char* P0 = lds + pb0;
    const unsigned char* Q0 = lds + (pb0 ^ 64u);

    // ---- stage 0, chunk 0 (windows 0..3 -> s0 rows 0..63) ----
    {
        f32x4 acc0 = bias, acc1 = bias, acc2 = bias, acc3 = bias;
        K_FULL(P0, Q0, 0,     acc0);
        K_FULL(P0, Q0, 4096,  acc1);
        K_FULL(P0, Q0, 8192,  acc2);
        K_FULL(P0, Q0, 12288, acc3);
        WRITE_ROW(R_S0, nl,      acc0);
        WRITE_ROW(R_S0, 16 + nl, acc1);
        WRITE_ROW(R_S0, 32 + nl, acc2);
        WRITE_ROW(R_S0, 48 + nl, acc3);
    }
    __syncthreads();   // B2: chunk-0 kin reads retired

    LOAD_KIN(64);      // chunk 1 (windows 4..7)
    __syncthreads();   // B3: chunk 1 ready

    // ---- stage 0, chunk 1 (windows 4..7 -> s0 rows 64..127) ----
    {
        f32x4 acc0 = bias, acc1 = bias, acc2 = bias, acc3 = bias;
        K_FULL(P0, Q0, 0,     acc0);
        K_FULL(P0, Q0, 4096,  acc1);
        K_FULL(P0, Q0, 8192,  acc2);
        K_FULL(P0, Q0, 12288, acc3);
        LOAD_WF(32768);   // prefetch stage-1 weights across the barrier
        WRITE_ROW(R_S0, 64 + nl,  acc0);
        WRITE_ROW(R_S0, 80 + nl,  acc1);
        WRITE_ROW(R_S0, 96 + nl,  acc2);
        WRITE_ROW(R_S0, 112 + nl, acc3);
    }
    __syncthreads();   // B4: s0 complete; kin dead

    // ---- stage 1: 128 -> 64 rows (4 n-tiles, deltas +8192) ----
    {
        unsigned pb = swz(R_S0 + ((unsigned)(2 * nl) << 8) + (unsigned)(kl << 4));
        const unsigned char* P = lds + pb;
        const unsigned char* Q = lds + (pb ^ 64u);
        f32x4 acc0 = {}, acc1 = {}, acc2 = {}, acc3 = {};
        K_FULL(P, Q, 0,     acc0);
        K_FULL(P, Q, 8192,  acc1);
        K_FULL(P, Q, 16384, acc2);
        K_FULL(P, Q, 24576, acc3);
        LOAD_WF(2 * 32768);
        WRITE_ROW(R_S1, nl,      acc0);
        WRITE_ROW(R_S1, 16 + nl, acc1);
        WRITE_ROW(R_S1, 32 + nl, acc2);
        WRITE_ROW(R_S1, 48 + nl, acc3);
    }
    __syncthreads();   // s1 done; s0 dead

    // ---- stage 2: 64 -> 32 rows ----
    {
        unsigned pb = swz(R_S1 + ((unsigned)(2 * nl) << 8) + (unsigned)(kl << 4));
        const unsigned char* P = lds + pb;
        const unsigned char* Q = lds + (pb ^ 64u);
        f32x4 acc0 = {}, acc1 = {};
        K_FULL(P, Q, 0,    acc0);
        K_FULL(P, Q, 8192, acc1);
        LOAD_WF(3 * 32768);
        WRITE_ROW(R_S2, nl,      acc0);
        WRITE_ROW(R_S2, 16 + nl, acc1);
    }
    __syncthreads();   // s2 done; s1 dead

    // ---- stage 3: 32 -> 16 rows ----
    {
        unsigned pb = swz(R_S2 + ((unsigned)(2 * nl) << 8) + (unsigned)(kl << 4));
        const unsigned char* P = lds + pb;
        const unsigned char* Q = lds + (pb ^ 64u);
        f32x4 acc0 = {};
        K_FULL(P, Q, 0, acc0);
        LOAD_WF(4 * 32768);
        WRITE_ROW(R_S3, nl, acc0);
    }
    __syncthreads();   // s3 done; s2 dead

    // ---- stage 4: 16 -> 8 rows (lanes nl>=8 clamped) ----
    {
        int dc = (nl < 8) ? nl : 7;
        unsigned pb = swz(R_S3 + ((unsigned)(2 * dc) << 8) + (unsigned)(kl << 4));
        const unsigned char* P = lds + pb;
        const unsigned char* Q = lds + (pb ^ 64u);
        f32x4 acc0 = {};
        K_FULL(P, Q, 0, acc0);
        // prefetch w_stop (4 frags) across the barrier
        #pragma unroll
        for (int kt = 0; kt < 4; ++kt)
            wf[kt] = *(const s16x8*)(wdb + 163840 + ct * 2048 + kt * 512 + lane * 8);
        if (nl < 8) WRITE_ROW(R_S4, nl, acc0);
    }
    __syncthreads();   // s4 done

    // ---- w_stop: 8 rows, K=128, no activation -> global f32 ----
    {
        int dc = (nl < 8) ? nl : 7;
        unsigned pb = swz(R_S4 + ((unsigned)dc << 8) + (unsigned)(kl << 4));
        const unsigned char* P = lds + pb;
        const unsigned char* Q = lds + (pb ^ 64u);
        f32x4 acc = {0.f, 0.f, 0.f, 0.f};
        K_HALF4(wf[0], wf[1], wf[2], wf[3], P, Q, 0, acc);
        int w = w0 + nl;
        if (nl < 8 && w < NWIN) {
            // lane holds channels ct*16+kl*4 .. +3 of window w: one dwordx4
            *(f32x4*)(out + ((size_t)bh * NBLK + (w + 1)) * DQ + ct * 16 + kl * 4) = acc;
        }
    }
#undef K_HALF4
#undef K_FULL
#undef WRITE_ROW
#undef LOAD_WF
#undef LOAD_KIN
}

extern "C" void kernel_launch(void* const* d_in, const int* in_sizes, int n_in,
                              void* d_out, int out_size, void* d_ws, size_t ws_size,
                              hipStream_t stream) {
    const float* kin   = (const float*)d_in[0];
    const float* pe    = (const float*)d_in[1];
    const float* wdown = (const float*)d_in[2];
    const float* wstop = (const float*)d_in[3];
    float* out = (float*)d_out;
    short* wbf  = (short*)d_ws;                       // 180224 shorts (frag-order)
    float* bias = (float*)((char*)d_ws + 360448);     // f32[2048]

    prep_kernel<<<728, 256, 0, stream>>>(wdown, wstop, pe, wbf, bias, out);
    fused_kernel<<<BQ * HQ * NWG_PER_HEAD, 512, 0, stream>>>(kin, wbf, bias, out);
}